// Round 13
// baseline (652.975 us; speedup 1.0000x reference)
//
#include <hip/hip_runtime.h>
#include <hip/hip_cooperative_groups.h>
#include <math.h>

namespace cg = cooperative_groups;

#define NEG_SLOPE 0.2f

typedef unsigned short ushort_t;
typedef __attribute__((ext_vector_type(8))) short short8v;   // 8 bf16 (4 VGPRs)
typedef __attribute__((ext_vector_type(4))) float f32x4;

__device__ inline ushort_t f2bf(float f) {
    unsigned b = __float_as_uint(f);
    unsigned r = (b + 0x7fffu + ((b >> 16) & 1u)) >> 16;
    return (ushort_t)r;
}
__device__ inline float bf2f(ushort_t u) { return __uint_as_float(((unsigned)u) << 16); }
__device__ inline float bflo(unsigned w) { return __uint_as_float(w << 16); }
__device__ inline float bfhi(unsigned w) { return __uint_as_float(w & 0xffff0000u); }

// ================= CSR build + weight prepack, single cooperative kernel =================
// B-frag layout for mfma_f32_16x16x32_bf16: lane = n(lo4) + 16*g, holds k = kt*32 + g*8 + j.
__global__ __launch_bounds__(256) void csr_coop_kernel(
    const int* __restrict__ ei, int E, int EP, int N, int NB,
    const float* __restrict__ W1, const float* __restrict__ W2,
    ushort_t* __restrict__ w1p, ushort_t* __restrict__ w2p,
    int* __restrict__ deg, int* __restrict__ bsum,
    int* __restrict__ rowptr, int* __restrict__ colsrc)
{
    cg::grid_group grid = cg::this_grid();
    __shared__ int wsum[4];
    __shared__ int sh[256];
    const int tid = threadIdx.x;
    const int gsz = gridDim.x * 256;
    const int gidx = blockIdx.x * 256 + tid;

    // phase 0: clear deg
    for (int i = gidx; i < N; i += gsz) deg[i] = 0;
    grid.sync();

    // phase 1: histogram + weight prepack
    for (int e = gidx; e < EP; e += gsz) {
        int d = (e < E) ? ei[E + e] : (e - E);
        atomicAdd(&deg[d], 1);
    }
    for (int i = gidx; i < 32768 + 12288; i += gsz) {
        if (i < 32768) {
            int j = i & 7, lane = (i >> 3) & 63, t = i >> 9;   // t = kt*16+nt
            int kt = t >> 4, nt = t & 15;
            int k = kt * 32 + (lane >> 4) * 8 + j;
            int n = nt * 16 + (lane & 15);
            w1p[i] = f2bf(W1[k * 256 + n]);
        } else {
            int ii = i - 32768;
            int j = ii & 7, lane = (ii >> 3) & 63, t = ii >> 9;  // t = kt*3+nt
            int kt = t / 3, nt = t - kt * 3;
            int k = kt * 32 + (lane >> 4) * 8 + j;
            int n = nt * 16 + (lane & 15);
            w2p[ii] = (n < 40) ? f2bf(W2[k * 40 + n]) : (ushort_t)0;
        }
    }
    grid.sync();

    // phase 2: per-256-chunk sums of deg
    for (int b = blockIdx.x; b < NB; b += gridDim.x) {
        int i = b * 256 + tid;
        int v = (i < N) ? deg[i] : 0;
#pragma unroll
        for (int off = 32; off > 0; off >>= 1) v += __shfl_xor(v, off, 64);
        if ((tid & 63) == 0) wsum[tid >> 6] = v;
        __syncthreads();
        if (tid == 0) bsum[b] = wsum[0] + wsum[1] + wsum[2] + wsum[3];
        __syncthreads();
    }
    grid.sync();

    // phase 3: block 0 scans bsum (NB <= 256) -> exclusive in place; rowptr[N] = total
    if (blockIdx.x == 0) {
        int v = (tid < NB) ? bsum[tid] : 0;
        sh[tid] = v;
        __syncthreads();
        for (int off = 1; off < 256; off <<= 1) {
            int t = (tid >= off) ? sh[tid - off] : 0;
            __syncthreads();
            sh[tid] += t;
            __syncthreads();
        }
        if (tid < NB) bsum[tid] = sh[tid] - v;
        if (tid == 0) rowptr[N] = sh[255];
    }
    grid.sync();

    // phase 4: rowptr = bsum[chunk] + local exclusive scan
    for (int b = blockIdx.x; b < NB; b += gridDim.x) {
        int i = b * 256 + tid;
        int v = (i < N) ? deg[i] : 0;
        sh[tid] = v;
        __syncthreads();
        for (int off = 1; off < 256; off <<= 1) {
            int t = (tid >= off) ? sh[tid - off] : 0;
            __syncthreads();
            sh[tid] += t;
            __syncthreads();
        }
        if (i < N) rowptr[i] = bsum[b] + sh[tid] - v;
        __syncthreads();
    }
    grid.sync();

    // phase 5: scatter (deg counts consumed)
    for (int e = gidx; e < EP; e += gsz) {
        int s, d;
        if (e < E) { s = ei[e]; d = ei[E + e]; } else { s = e - E; d = e - E; }
        int old = atomicSub(&deg[d], 1);
        colsrc[rowptr[d] + old - 1] = s;
    }
}

// ====== layer 1 GEMM via MFMA: 64 rows/block, wave = 16 rows x 256 cols ======
__global__ __launch_bounds__(256) void gemm1_mfma(
    const float* __restrict__ x, const ushort_t* __restrict__ w1p,
    const float* __restrict__ att_src, const float* __restrict__ att_dst,
    ushort_t* __restrict__ h1b, float* __restrict__ asrc, float* __restrict__ adst, int N)
{
    __shared__ ushort_t xs[64][136];
    const int n0 = blockIdx.x * 64;
    const int tid = threadIdx.x;
    const int lane = tid & 63;
    const int w = tid >> 6;
    const int l16 = lane & 15;
    const int g = lane >> 4;

#pragma unroll
    for (int it = 0; it < 8; it++) {
        int idx = tid + it * 256;
        int row = idx >> 5, c4 = (idx & 31) * 4;
        float4 v = *(const float4*)(x + (size_t)(n0 + row) * 128 + c4);
        ushort4 u = {f2bf(v.x), f2bf(v.y), f2bf(v.z), f2bf(v.w)};
        *(ushort4*)&xs[row][c4] = u;
    }
    __syncthreads();

    short8v afr[4];
#pragma unroll
    for (int kt = 0; kt < 4; kt++)
        afr[kt] = *(const short8v*)&xs[w * 16 + l16][kt * 32 + g * 8];

    f32x4 acc[16];
#pragma unroll
    for (int nt = 0; nt < 16; nt++) acc[nt] = (f32x4){0.f, 0.f, 0.f, 0.f};

    const short8v* wp = (const short8v*)w1p;
#pragma unroll
    for (int nt = 0; nt < 16; nt++) {
        short8v b0 = wp[(0 * 16 + nt) * 64 + lane];
        short8v b1 = wp[(1 * 16 + nt) * 64 + lane];
        short8v b2 = wp[(2 * 16 + nt) * 64 + lane];
        short8v b3 = wp[(3 * 16 + nt) * 64 + lane];
        acc[nt] = __builtin_amdgcn_mfma_f32_16x16x32_bf16(afr[0], b0, acc[nt], 0, 0, 0);
        acc[nt] = __builtin_amdgcn_mfma_f32_16x16x32_bf16(afr[1], b1, acc[nt], 0, 0, 0);
        acc[nt] = __builtin_amdgcn_mfma_f32_16x16x32_bf16(afr[2], b2, acc[nt], 0, 0, 0);
        acc[nt] = __builtin_amdgcn_mfma_f32_16x16x32_bf16(afr[3], b3, acc[nt], 0, 0, 0);
    }

    float ps[4][4], pd[4][4];
#pragma unroll
    for (int r = 0; r < 4; r++)
#pragma unroll
        for (int h = 0; h < 4; h++) { ps[r][h] = 0.f; pd[r][h] = 0.f; }

#pragma unroll
    for (int nt = 0; nt < 16; nt++) {
        const int col = nt * 16 + l16;
        const float as_c = att_src[col];
        const float ad_c = att_dst[col];
        const int h = nt >> 2;
#pragma unroll
        for (int r = 0; r < 4; r++) {
            float v = acc[nt][r];
            h1b[(size_t)(n0 + w * 16 + g * 4 + r) * 256 + col] = f2bf(v);
            ps[r][h] += v * as_c;
            pd[r][h] += v * ad_c;
        }
    }
#pragma unroll
    for (int r = 0; r < 4; r++)
#pragma unroll
        for (int h = 0; h < 4; h++)
#pragma unroll
            for (int off = 8; off > 0; off >>= 1) {
                ps[r][h] += __shfl_xor(ps[r][h], off, 64);
                pd[r][h] += __shfl_xor(pd[r][h], off, 64);
            }

    const int sel = l16 >> 2;
#pragma unroll
    for (int hh = 0; hh < 4; hh++) {
        if (hh == (l16 & 3)) {
            if (sel == 0) {
#pragma unroll
                for (int r = 0; r < 4; r++)
                    asrc[(size_t)(n0 + w * 16 + g * 4 + r) * 4 + hh] = ps[r][hh];
            } else if (sel == 1) {
#pragma unroll
                for (int r = 0; r < 4; r++)
                    adst[(size_t)(n0 + w * 16 + g * 4 + r) * 4 + hh] = pd[r][hh];
            }
        }
    }
}

// ====== layer 1 aggregation: 2 edges/half-wave, 8 edges/iter; a1 written bf16 ======
__global__ __launch_bounds__(256) void node_agg1(
    const int* __restrict__ rowptr, const int* __restrict__ colsrc,
    const float* __restrict__ asrc, const float* __restrict__ adst,
    const ushort_t* __restrict__ h1b, const float* __restrict__ b1,
    ushort_t* __restrict__ a1b, int N)
{
    int n = (blockIdx.x * 256 + threadIdx.x) >> 6;
    int lane = threadIdx.x & 63;
    if (n >= N) return;
    const int r0 = rowptr[n], r1 = rowptr[n + 1];
    const int half = lane >> 5;
    const int l5 = lane & 31;
    const int head = l5 >> 3;
    const int coff = head * 64 + (l5 & 7) * 8;
    const float adhh = adst[(size_t)n * 4 + head];

    float acc[8] = {0.f, 0.f, 0.f, 0.f, 0.f, 0.f, 0.f, 0.f};
    float ssum = 0.f;
    int j = r0;
    for (; j + 8 <= r1; j += 8) {
        int jA = j + half, jB = j + 2 + half, jC = j + 4 + half, jD = j + 6 + half;
        int sA = colsrc[jA], sB = colsrc[jB], sC = colsrc[jC], sD = colsrc[jD];
        float aA = asrc[(size_t)sA * 4 + head];
        float aB = asrc[(size_t)sB * 4 + head];
        float aC = asrc[(size_t)sC * 4 + head];
        float aD = asrc[(size_t)sD * 4 + head];
        uint4 qA = *(const uint4*)&h1b[(size_t)sA * 256 + coff];
        uint4 qB = *(const uint4*)&h1b[(size_t)sB * 256 + coff];
        uint4 qC = *(const uint4*)&h1b[(size_t)sC * 256 + coff];
        uint4 qD = *(const uint4*)&h1b[(size_t)sD * 256 + coff];
        float vA = aA + adhh; vA = vA > 0.f ? vA : NEG_SLOPE * vA;
        float vB = aB + adhh; vB = vB > 0.f ? vB : NEG_SLOPE * vB;
        float vC = aC + adhh; vC = vC > 0.f ? vC : NEG_SLOPE * vC;
        float vD = aD + adhh; vD = vD > 0.f ? vD : NEG_SLOPE * vD;
        float pA = __expf(vA), pB = __expf(vB), pC = __expf(vC), pD = __expf(vD);
        ssum += (pA + pB) + (pC + pD);
        acc[0] += pA * bflo(qA.x) + pB * bflo(qB.x) + pC * bflo(qC.x) + pD * bflo(qD.x);
        acc[1] += pA * bfhi(qA.x) + pB * bfhi(qB.x) + pC * bfhi(qC.x) + pD * bfhi(qD.x);
        acc[2] += pA * bflo(qA.y) + pB * bflo(qB.y) + pC * bflo(qC.y) + pD * bflo(qD.y);
        acc[3] += pA * bfhi(qA.y) + pB * bfhi(qB.y) + pC * bfhi(qC.y) + pD * bfhi(qD.y);
        acc[4] += pA * bflo(qA.z) + pB * bflo(qB.z) + pC * bflo(qC.z) + pD * bflo(qD.z);
        acc[5] += pA * bfhi(qA.z) + pB * bfhi(qB.z) + pC * bfhi(qC.z) + pD * bfhi(qD.z);
        acc[6] += pA * bflo(qA.w) + pB * bflo(qB.w) + pC * bflo(qC.w) + pD * bflo(qD.w);
        acc[7] += pA * bfhi(qA.w) + pB * bfhi(qB.w) + pC * bfhi(qC.w) + pD * bfhi(qD.w);
    }
    for (; j < r1; j += 2) {
        int jj = j + half;
        bool valid = jj < r1;
        int s = colsrc[valid ? jj : r0];
        float a = asrc[(size_t)s * 4 + head];
        uint4 q = *(const uint4*)&h1b[(size_t)s * 256 + coff];
        float v = a + adhh; v = v > 0.f ? v : NEG_SLOPE * v;
        float p = valid ? __expf(v) : 0.f;
        ssum += p;
        acc[0] += p * bflo(q.x);
        acc[1] += p * bfhi(q.x);
        acc[2] += p * bflo(q.y);
        acc[3] += p * bfhi(q.y);
        acc[4] += p * bflo(q.z);
        acc[5] += p * bfhi(q.z);
        acc[6] += p * bflo(q.w);
        acc[7] += p * bfhi(q.w);
    }

#pragma unroll
    for (int k = 0; k < 8; k++) acc[k] += __shfl_xor(acc[k], 32, 64);
    ssum += __shfl_xor(ssum, 32, 64);
    const float rz = 1.f / ssum;

    float s0 = half ? acc[4] : acc[0];
    float s1 = half ? acc[5] : acc[1];
    float s2 = half ? acc[6] : acc[2];
    float s3 = half ? acc[7] : acc[3];
    const int wc = coff + half * 4;
    const float4 bv = *(const float4*)&b1[wc];
    float o0 = s0 * rz + bv.x;
    float o1 = s1 * rz + bv.y;
    float o2 = s2 * rz + bv.z;
    float o3 = s3 * rz + bv.w;
    ushort4 outv = {f2bf(o0 > 0.f ? o0 : 0.f), f2bf(o1 > 0.f ? o1 : 0.f),
                    f2bf(o2 > 0.f ? o2 : 0.f), f2bf(o3 > 0.f ? o3 : 0.f)};
    *(ushort4*)&a1b[(size_t)n * 256 + wc] = outv;
}

// ====== layer 2 GEMM via MFMA: A is bf16, 64 rows/block, N padded to 48, K=256 ======
__global__ __launch_bounds__(256) void gemm2_mfma(
    const ushort_t* __restrict__ A, const ushort_t* __restrict__ w2p,
    const float* __restrict__ as2, const float* __restrict__ ad2,
    ushort_t* __restrict__ h2b, float* __restrict__ asrc, float* __restrict__ adst, int N)
{
    __shared__ ushort_t xs[64][264];
    const int n0 = blockIdx.x * 64;
    const int tid = threadIdx.x;
    const int lane = tid & 63;
    const int w = tid >> 6;
    const int l16 = lane & 15;
    const int g = lane >> 4;

#pragma unroll
    for (int it = 0; it < 8; it++) {
        int idx = tid + it * 256;
        int row = idx >> 5, c8 = (idx & 31) * 8;
        uint4 v = *(const uint4*)(A + (size_t)(n0 + row) * 256 + c8);
        *(uint4*)&xs[row][c8] = v;
    }
    __syncthreads();

    short8v afr[8];
#pragma unroll
    for (int kt = 0; kt < 8; kt++)
        afr[kt] = *(const short8v*)&xs[w * 16 + l16][kt * 32 + g * 8];

    f32x4 acc[3];
#pragma unroll
    for (int nt = 0; nt < 3; nt++) acc[nt] = (f32x4){0.f, 0.f, 0.f, 0.f};

    const short8v* wp = (const short8v*)w2p;
#pragma unroll
    for (int nt = 0; nt < 3; nt++) {
#pragma unroll
        for (int kt = 0; kt < 8; kt++) {
            short8v b = wp[(kt * 3 + nt) * 64 + lane];
            acc[nt] = __builtin_amdgcn_mfma_f32_16x16x32_bf16(afr[kt], b, acc[nt], 0, 0, 0);
        }
    }

    float ps[4] = {0.f, 0.f, 0.f, 0.f}, pd[4] = {0.f, 0.f, 0.f, 0.f};
#pragma unroll
    for (int nt = 0; nt < 3; nt++) {
        const int col = nt * 16 + l16;
        const bool ok = col < 40;
        const float as_c = ok ? as2[col] : 0.f;
        const float ad_c = ok ? ad2[col] : 0.f;
#pragma unroll
        for (int r = 0; r < 4; r++) {
            float v = acc[nt][r];
            if (ok) h2b[(size_t)(n0 + w * 16 + g * 4 + r) * 40 + col] = f2bf(v);
            ps[r] += v * as_c;
            pd[r] += v * ad_c;
        }
    }
#pragma unroll
    for (int r = 0; r < 4; r++)
#pragma unroll
        for (int off = 8; off > 0; off >>= 1) {
            ps[r] += __shfl_xor(ps[r], off, 64);
            pd[r] += __shfl_xor(pd[r], off, 64);
        }
    if (l16 == 0) {
#pragma unroll
        for (int r = 0; r < 4; r++) asrc[n0 + w * 16 + g * 4 + r] = ps[r];
    } else if (l16 == 1) {
#pragma unroll
        for (int r = 0; r < 4; r++) adst[n0 + w * 16 + g * 4 + r] = pd[r];
    }
}

// ====== layer 2 aggregation: 2 edges/half-wave, 8 edges/iter ======
__global__ __launch_bounds__(256) void node_agg2(
    const int* __restrict__ rowptr, const int* __restrict__ colsrc,
    const float* __restrict__ asrc, const float* __restrict__ adst,
    const ushort_t* __restrict__ h2b, const float* __restrict__ b2,
    float* __restrict__ out, int N)
{
    int n = (blockIdx.x * 256 + threadIdx.x) >> 6;
    int lane = threadIdx.x & 63;
    if (n >= N) return;
    const int r0 = rowptr[n], r1 = rowptr[n + 1];
    const int half = lane >> 5;
    const int l5 = lane & 31;
    const bool act = l5 < 20;
    const int cc = act ? 2 * l5 : 0;
    const float ad = adst[n];

    float acc0 = 0.f, acc1 = 0.f, ssum = 0.f;
    int j = r0;
    for (; j + 8 <= r1; j += 8) {
        int jA = j + half, jB = j + 2 + half, jC = j + 4 + half, jD = j + 6 + half;
        int sA = colsrc[jA], sB = colsrc[jB], sC = colsrc[jC], sD = colsrc[jD];
        float eA = asrc[sA] + ad, eB = asrc[sB] + ad, eC = asrc[sC] + ad, eD = asrc[sD] + ad;
        unsigned qA = *(const unsigned*)&h2b[(size_t)sA * 40 + cc];
        unsigned qB = *(const unsigned*)&h2b[(size_t)sB * 40 + cc];
        unsigned qC = *(const unsigned*)&h2b[(size_t)sC * 40 + cc];
        unsigned qD = *(const unsigned*)&h2b[(size_t)sD * 40 + cc];
        eA = eA > 0.f ? eA : NEG_SLOPE * eA;
        eB = eB > 0.f ? eB : NEG_SLOPE * eB;
        eC = eC > 0.f ? eC : NEG_SLOPE * eC;
        eD = eD > 0.f ? eD : NEG_SLOPE * eD;
        float pA = __expf(eA), pB = __expf(eB), pC = __expf(eC), pD = __expf(eD);
        ssum += (pA + pB) + (pC + pD);
        acc0 += pA * bflo(qA) + pB * bflo(qB) + pC * bflo(qC) + pD * bflo(qD);
        acc1 += pA * bfhi(qA) + pB * bfhi(qB) + pC * bfhi(qC) + pD * bfhi(qD);
    }
    for (; j < r1; j += 2) {
        int jj = j + half;
        bool valid = jj < r1;
        int s = colsrc[valid ? jj : r0];
        float e = asrc[s] + ad;
        unsigned q = *(const unsigned*)&h2b[(size_t)s * 40 + cc];
        e = e > 0.f ? e : NEG_SLOPE * e;
        float p = valid ? __expf(e) : 0.f;
        ssum += p;
        acc0 += p * bflo(q);
        acc1 += p * bfhi(q);
    }

    acc0 += __shfl_xor(acc0, 32, 64);
    acc1 += __shfl_xor(acc1, 32, 64);
    ssum += __shfl_xor(ssum, 32, 64);
    const float rz = 1.f / ssum;

    float v0 = act ? acc0 * rz + b2[cc]     : -1.0e30f;
    float v1 = act ? acc1 * rz + b2[cc + 1] : -1.0e30f;
    float mx = fmaxf(v0, v1);
#pragma unroll
    for (int off = 16; off > 0; off >>= 1) mx = fmaxf(mx, __shfl_xor(mx, off, 64));
    float pe = act ? __expf(v0 - mx) + __expf(v1 - mx) : 0.f;
#pragma unroll
    for (int off = 16; off > 0; off >>= 1) pe += __shfl_xor(pe, off, 64);
    float lse = mx + logf(pe);
    if (act && half == 0) {
        float2 o = make_float2(v0 - lse, v1 - lse);
        *(float2*)&out[(size_t)n * 40 + cc] = o;
    }
}

extern "C" void kernel_launch(void* const* d_in, const int* in_sizes, int n_in,
                              void* d_out, int out_size, void* d_ws, size_t ws_size,
                              hipStream_t stream)
{
    const float* x   = (const float*)d_in[0];
    const int*   ei  = (const int*)d_in[1];
    const float* W1  = (const float*)d_in[2];
    const float* as1 = (const float*)d_in[3];
    const float* ad1 = (const float*)d_in[4];
    const float* b1  = (const float*)d_in[5];
    const float* W2  = (const float*)d_in[6];
    const float* as2 = (const float*)d_in[7];
    const float* ad2 = (const float*)d_in[8];
    const float* b2  = (const float*)d_in[9];
    float* out = (float*)d_out;

    const int N  = in_sizes[0] / 128;
    const int E  = in_sizes[1] / 2;
    const int EP = E + N;
    const int NB = (N + 255) / 256;

    // workspace layout
    char* ws = (char*)d_ws;
    ushort_t* h1b  = (ushort_t*)ws;                        // N*256 bf16
    ushort_t* a1b  = h1b + (size_t)N * 256;                // N*256 bf16
    float* asrc    = (float*)(a1b + (size_t)N * 256);      // N*4
    float* adst    = asrc + (size_t)N * 4;                 // N*4
    int*   rowptr  = (int*)(adst + (size_t)N * 4);         // N+1
    int*   colsrc  = rowptr + (N + 1);                     // EP
    int*   deg     = colsrc + EP;                          // N
    ushort_t* h2b  = (ushort_t*)(deg + N);                 // N*40 bf16
    int*   bsum    = (int*)(h2b + (size_t)N * 40 + 16);    // NB (+pad for OOB-safe uint reads)
    ushort_t* w1p  = (ushort_t*)(bsum + NB);               // 32768 bf16
    ushort_t* w2p  = w1p + 32768;                          // 12288 bf16

    // ---- CSR build + weight prepack: one cooperative kernel ----
    {
        int E_ = E, EP_ = EP, N_ = N, NB_ = NB;
        const int* ei_ = ei;
        const float* W1_ = W1;
        const float* W2_ = W2;
        ushort_t* w1p_ = w1p;
        ushort_t* w2p_ = w2p;
        int* deg_ = deg;
        int* bsum_ = bsum;
        int* rowptr_ = rowptr;
        int* colsrc_ = colsrc;
        void* args[] = {&ei_, &E_, &EP_, &N_, &NB_, &W1_, &W2_,
                        &w1p_, &w2p_, &deg_, &bsum_, &rowptr_, &colsrc_};
        hipLaunchCooperativeKernel((const void*)csr_coop_kernel,
                                   dim3(1024), dim3(256), args, 0, stream);
    }

    // ---- layer 1 ----
    gemm1_mfma<<<N / 64, 256, 0, stream>>>(x, w1p, as1, ad1, h1b, asrc, adst, N);
    node_agg1<<<(N * 64 + 255) / 256, 256, 0, stream>>>(rowptr, colsrc, asrc, adst, h1b, b1, a1b, N);

    // ---- layer 2 ----
    gemm2_mfma<<<N / 64, 256, 0, stream>>>(a1b, w2p, as2, ad2, h2b, asrc, adst, N);
    node_agg2<<<(N * 64 + 255) / 256, 256, 0, stream>>>(rowptr, colsrc, asrc, adst, h2b, b2, out, N);
}

// Round 14
// 182.096 us; speedup vs baseline: 3.5859x; 3.5859x over previous
//
#include <hip/hip_runtime.h>
#include <math.h>

#define NEG_SLOPE 0.2f

typedef unsigned short ushort_t;
typedef __attribute__((ext_vector_type(8))) short short8v;   // 8 bf16 (4 VGPRs)
typedef __attribute__((ext_vector_type(4))) float f32x4;

__device__ inline ushort_t f2bf(float f) {
    unsigned b = __float_as_uint(f);
    unsigned r = (b + 0x7fffu + ((b >> 16) & 1u)) >> 16;
    return (ushort_t)r;
}
__device__ inline float bf2f(ushort_t u) { return __uint_as_float(((unsigned)u) << 16); }
__device__ inline float bflo(unsigned w) { return __uint_as_float(w << 16); }
__device__ inline float bfhi(unsigned w) { return __uint_as_float(w & 0xffff0000u); }

// ================= CSR build (+ fused weight prepack) =================
// B-frag layout for mfma_f32_16x16x32_bf16: lane = n(lo4) + 16*g, holds k = kt*32 + g*8 + j.
__global__ void hist_prepack_kernel(const int* __restrict__ ei, int E, int EP,
                                    int* __restrict__ deg,
                                    const float* __restrict__ W1, const float* __restrict__ W2,
                                    ushort_t* __restrict__ w1p, ushort_t* __restrict__ w2p)
{
    int e = blockIdx.x * 256 + threadIdx.x;
    if (e < EP) {
        int d = (e < E) ? ei[E + e] : (e - E);
        atomicAdd(&deg[d], 1);
    }
    if (e < 32768) {
        int j = e & 7, lane = (e >> 3) & 63, t = e >> 9;   // t = kt*16+nt
        int kt = t >> 4, nt = t & 15;
        int k = kt * 32 + (lane >> 4) * 8 + j;
        int n = nt * 16 + (lane & 15);
        w1p[e] = f2bf(W1[k * 256 + n]);
    } else if (e < 32768 + 12288) {
        int ii = e - 32768;
        int j = ii & 7, lane = (ii >> 3) & 63, t = ii >> 9;  // t = kt*3+nt
        int kt = t / 3, nt = t - kt * 3;
        int k = kt * 32 + (lane >> 4) * 8 + j;
        int n = nt * 16 + (lane & 15);
        w2p[ii] = (n < 40) ? f2bf(W2[k * 40 + n]) : (ushort_t)0;
    }
}

__global__ void block_sum_kernel(const int* __restrict__ deg, int* __restrict__ bsum, int N)
{
    int i = blockIdx.x * 256 + threadIdx.x;
    int v = (i < N) ? deg[i] : 0;
#pragma unroll
    for (int off = 32; off > 0; off >>= 1) v += __shfl_xor(v, off, 64);
    __shared__ int wsum[4];
    if ((threadIdx.x & 63) == 0) wsum[threadIdx.x >> 6] = v;
    __syncthreads();
    if (threadIdx.x == 0) bsum[blockIdx.x] = wsum[0] + wsum[1] + wsum[2] + wsum[3];
}

// per-block: (a) scan the nb chunk-sums redundantly in LDS, (b) local scan of own chunk,
// (c) rowptr = global exclusive prefix. Block 0 also writes rowptr[N] = total.
__global__ void block_scan_kernel(const int* __restrict__ deg, const int* __restrict__ bsum,
                                  int* __restrict__ rowptr, int N, int nb)
{
    __shared__ int sb[256];
    __shared__ int sh[256];
    const int tid = threadIdx.x;
    int bv = (tid < nb) ? bsum[tid] : 0;
    sb[tid] = bv;
    int i = blockIdx.x * 256 + tid;
    int v = (i < N) ? deg[i] : 0;
    sh[tid] = v;
    __syncthreads();
    for (int off = 1; off < 256; off <<= 1) {
        int tb = (tid >= off) ? sb[tid - off] : 0;
        int tv = (tid >= off) ? sh[tid - off] : 0;
        __syncthreads();
        sb[tid] += tb;
        sh[tid] += tv;
        __syncthreads();
    }
    int blkoff = (blockIdx.x == 0) ? 0 : sb[blockIdx.x - 1];
    if (i < N) rowptr[i] = blkoff + sh[tid] - v;   // exclusive
    if (blockIdx.x == 0 && tid == 0) rowptr[N] = sb[nb - 1];
}

__global__ void scatter_kernel(const int* __restrict__ ei, int E, int EP,
                               const int* __restrict__ rowptr, int* __restrict__ deg,
                               int* __restrict__ colsrc)
{
    int e = blockIdx.x * 256 + threadIdx.x;
    if (e >= EP) return;
    int s, d;
    if (e < E) { s = ei[e]; d = ei[E + e]; } else { s = e - E; d = e - E; }
    int old = atomicSub(&deg[d], 1);
    colsrc[rowptr[d] + old - 1] = s;
}

// ====== layer 1 GEMM via MFMA: 64 rows/block, wave = 16 rows x 256 cols ======
__global__ __launch_bounds__(256) void gemm1_mfma(
    const float* __restrict__ x, const ushort_t* __restrict__ w1p,
    const float* __restrict__ att_src, const float* __restrict__ att_dst,
    ushort_t* __restrict__ h1b, float* __restrict__ asrc, float* __restrict__ adst, int N)
{
    __shared__ ushort_t xs[64][136];
    const int n0 = blockIdx.x * 64;
    const int tid = threadIdx.x;
    const int lane = tid & 63;
    const int w = tid >> 6;
    const int l16 = lane & 15;
    const int g = lane >> 4;

#pragma unroll
    for (int it = 0; it < 8; it++) {
        int idx = tid + it * 256;
        int row = idx >> 5, c4 = (idx & 31) * 4;
        float4 v = *(const float4*)(x + (size_t)(n0 + row) * 128 + c4);
        ushort4 u = {f2bf(v.x), f2bf(v.y), f2bf(v.z), f2bf(v.w)};
        *(ushort4*)&xs[row][c4] = u;
    }
    __syncthreads();

    short8v afr[4];
#pragma unroll
    for (int kt = 0; kt < 4; kt++)
        afr[kt] = *(const short8v*)&xs[w * 16 + l16][kt * 32 + g * 8];

    f32x4 acc[16];
#pragma unroll
    for (int nt = 0; nt < 16; nt++) acc[nt] = (f32x4){0.f, 0.f, 0.f, 0.f};

    const short8v* wp = (const short8v*)w1p;
#pragma unroll
    for (int nt = 0; nt < 16; nt++) {
        short8v b0 = wp[(0 * 16 + nt) * 64 + lane];
        short8v b1 = wp[(1 * 16 + nt) * 64 + lane];
        short8v b2 = wp[(2 * 16 + nt) * 64 + lane];
        short8v b3 = wp[(3 * 16 + nt) * 64 + lane];
        acc[nt] = __builtin_amdgcn_mfma_f32_16x16x32_bf16(afr[0], b0, acc[nt], 0, 0, 0);
        acc[nt] = __builtin_amdgcn_mfma_f32_16x16x32_bf16(afr[1], b1, acc[nt], 0, 0, 0);
        acc[nt] = __builtin_amdgcn_mfma_f32_16x16x32_bf16(afr[2], b2, acc[nt], 0, 0, 0);
        acc[nt] = __builtin_amdgcn_mfma_f32_16x16x32_bf16(afr[3], b3, acc[nt], 0, 0, 0);
    }

    float ps[4][4], pd[4][4];
#pragma unroll
    for (int r = 0; r < 4; r++)
#pragma unroll
        for (int h = 0; h < 4; h++) { ps[r][h] = 0.f; pd[r][h] = 0.f; }

#pragma unroll
    for (int nt = 0; nt < 16; nt++) {
        const int col = nt * 16 + l16;
        const float as_c = att_src[col];
        const float ad_c = att_dst[col];
        const int h = nt >> 2;
#pragma unroll
        for (int r = 0; r < 4; r++) {
            float v = acc[nt][r];
            h1b[(size_t)(n0 + w * 16 + g * 4 + r) * 256 + col] = f2bf(v);
            ps[r][h] += v * as_c;
            pd[r][h] += v * ad_c;
        }
    }
#pragma unroll
    for (int r = 0; r < 4; r++)
#pragma unroll
        for (int h = 0; h < 4; h++)
#pragma unroll
            for (int off = 8; off > 0; off >>= 1) {
                ps[r][h] += __shfl_xor(ps[r][h], off, 64);
                pd[r][h] += __shfl_xor(pd[r][h], off, 64);
            }

    const int sel = l16 >> 2;
#pragma unroll
    for (int hh = 0; hh < 4; hh++) {
        if (hh == (l16 & 3)) {
            if (sel == 0) {
#pragma unroll
                for (int r = 0; r < 4; r++)
                    asrc[(size_t)(n0 + w * 16 + g * 4 + r) * 4 + hh] = ps[r][hh];
            } else if (sel == 1) {
#pragma unroll
                for (int r = 0; r < 4; r++)
                    adst[(size_t)(n0 + w * 16 + g * 4 + r) * 4 + hh] = pd[r][hh];
            }
        }
    }
}

// ====== layer 1 aggregation: 2 edges/half-wave, 8 edges/iter; a1 written bf16 ======
__global__ __launch_bounds__(256) void node_agg1(
    const int* __restrict__ rowptr, const int* __restrict__ colsrc,
    const float* __restrict__ asrc, const float* __restrict__ adst,
    const ushort_t* __restrict__ h1b, const float* __restrict__ b1,
    ushort_t* __restrict__ a1b, int N)
{
    int n = (blockIdx.x * 256 + threadIdx.x) >> 6;
    int lane = threadIdx.x & 63;
    if (n >= N) return;
    const int r0 = rowptr[n], r1 = rowptr[n + 1];
    const int half = lane >> 5;
    const int l5 = lane & 31;
    const int head = l5 >> 3;
    const int coff = head * 64 + (l5 & 7) * 8;
    const float adhh = adst[(size_t)n * 4 + head];

    float acc[8] = {0.f, 0.f, 0.f, 0.f, 0.f, 0.f, 0.f, 0.f};
    float ssum = 0.f;
    int j = r0;
    for (; j + 8 <= r1; j += 8) {
        int jA = j + half, jB = j + 2 + half, jC = j + 4 + half, jD = j + 6 + half;
        int sA = colsrc[jA], sB = colsrc[jB], sC = colsrc[jC], sD = colsrc[jD];
        float aA = asrc[(size_t)sA * 4 + head];
        float aB = asrc[(size_t)sB * 4 + head];
        float aC = asrc[(size_t)sC * 4 + head];
        float aD = asrc[(size_t)sD * 4 + head];
        uint4 qA = *(const uint4*)&h1b[(size_t)sA * 256 + coff];
        uint4 qB = *(const uint4*)&h1b[(size_t)sB * 256 + coff];
        uint4 qC = *(const uint4*)&h1b[(size_t)sC * 256 + coff];
        uint4 qD = *(const uint4*)&h1b[(size_t)sD * 256 + coff];
        float vA = aA + adhh; vA = vA > 0.f ? vA : NEG_SLOPE * vA;
        float vB = aB + adhh; vB = vB > 0.f ? vB : NEG_SLOPE * vB;
        float vC = aC + adhh; vC = vC > 0.f ? vC : NEG_SLOPE * vC;
        float vD = aD + adhh; vD = vD > 0.f ? vD : NEG_SLOPE * vD;
        float pA = __expf(vA), pB = __expf(vB), pC = __expf(vC), pD = __expf(vD);
        ssum += (pA + pB) + (pC + pD);
        acc[0] += pA * bflo(qA.x) + pB * bflo(qB.x) + pC * bflo(qC.x) + pD * bflo(qD.x);
        acc[1] += pA * bfhi(qA.x) + pB * bfhi(qB.x) + pC * bfhi(qC.x) + pD * bfhi(qD.x);
        acc[2] += pA * bflo(qA.y) + pB * bflo(qB.y) + pC * bflo(qC.y) + pD * bflo(qD.y);
        acc[3] += pA * bfhi(qA.y) + pB * bfhi(qB.y) + pC * bfhi(qC.y) + pD * bfhi(qD.y);
        acc[4] += pA * bflo(qA.z) + pB * bflo(qB.z) + pC * bflo(qC.z) + pD * bflo(qD.z);
        acc[5] += pA * bfhi(qA.z) + pB * bfhi(qB.z) + pC * bfhi(qC.z) + pD * bfhi(qD.z);
        acc[6] += pA * bflo(qA.w) + pB * bflo(qB.w) + pC * bflo(qC.w) + pD * bflo(qD.w);
        acc[7] += pA * bfhi(qA.w) + pB * bfhi(qB.w) + pC * bfhi(qC.w) + pD * bfhi(qD.w);
    }
    for (; j < r1; j += 2) {
        int jj = j + half;
        bool valid = jj < r1;
        int s = colsrc[valid ? jj : r0];
        float a = asrc[(size_t)s * 4 + head];
        uint4 q = *(const uint4*)&h1b[(size_t)s * 256 + coff];
        float v = a + adhh; v = v > 0.f ? v : NEG_SLOPE * v;
        float p = valid ? __expf(v) : 0.f;
        ssum += p;
        acc[0] += p * bflo(q.x);
        acc[1] += p * bfhi(q.x);
        acc[2] += p * bflo(q.y);
        acc[3] += p * bfhi(q.y);
        acc[4] += p * bflo(q.z);
        acc[5] += p * bfhi(q.z);
        acc[6] += p * bflo(q.w);
        acc[7] += p * bfhi(q.w);
    }

#pragma unroll
    for (int k = 0; k < 8; k++) acc[k] += __shfl_xor(acc[k], 32, 64);
    ssum += __shfl_xor(ssum, 32, 64);
    const float rz = 1.f / ssum;

    float s0 = half ? acc[4] : acc[0];
    float s1 = half ? acc[5] : acc[1];
    float s2 = half ? acc[6] : acc[2];
    float s3 = half ? acc[7] : acc[3];
    const int wc = coff + half * 4;
    const float4 bv = *(const float4*)&b1[wc];
    float o0 = s0 * rz + bv.x;
    float o1 = s1 * rz + bv.y;
    float o2 = s2 * rz + bv.z;
    float o3 = s3 * rz + bv.w;
    ushort4 outv = {f2bf(o0 > 0.f ? o0 : 0.f), f2bf(o1 > 0.f ? o1 : 0.f),
                    f2bf(o2 > 0.f ? o2 : 0.f), f2bf(o3 > 0.f ? o3 : 0.f)};
    *(ushort4*)&a1b[(size_t)n * 256 + wc] = outv;
}

// ====== layer 2 GEMM via MFMA: A is bf16, 64 rows/block, N padded to 48, K=256 ======
__global__ __launch_bounds__(256) void gemm2_mfma(
    const ushort_t* __restrict__ A, const ushort_t* __restrict__ w2p,
    const float* __restrict__ as2, const float* __restrict__ ad2,
    ushort_t* __restrict__ h2b, float* __restrict__ asrc, float* __restrict__ adst, int N)
{
    __shared__ ushort_t xs[64][264];
    const int n0 = blockIdx.x * 64;
    const int tid = threadIdx.x;
    const int lane = tid & 63;
    const int w = tid >> 6;
    const int l16 = lane & 15;
    const int g = lane >> 4;

    // stage a1 (64x256 bf16) -> LDS, 16B per lane
#pragma unroll
    for (int it = 0; it < 8; it++) {
        int idx = tid + it * 256;             // over 2048 uint4-of-bf16 (8 elems)
        int row = idx >> 5, c8 = (idx & 31) * 8;
        uint4 v = *(const uint4*)(A + (size_t)(n0 + row) * 256 + c8);
        *(uint4*)&xs[row][c8] = v;
    }
    __syncthreads();

    short8v afr[8];
#pragma unroll
    for (int kt = 0; kt < 8; kt++)
        afr[kt] = *(const short8v*)&xs[w * 16 + l16][kt * 32 + g * 8];

    f32x4 acc[3];
#pragma unroll
    for (int nt = 0; nt < 3; nt++) acc[nt] = (f32x4){0.f, 0.f, 0.f, 0.f};

    const short8v* wp = (const short8v*)w2p;
#pragma unroll
    for (int nt = 0; nt < 3; nt++) {
#pragma unroll
        for (int kt = 0; kt < 8; kt++) {
            short8v b = wp[(kt * 3 + nt) * 64 + lane];
            acc[nt] = __builtin_amdgcn_mfma_f32_16x16x32_bf16(afr[kt], b, acc[nt], 0, 0, 0);
        }
    }

    float ps[4] = {0.f, 0.f, 0.f, 0.f}, pd[4] = {0.f, 0.f, 0.f, 0.f};
#pragma unroll
    for (int nt = 0; nt < 3; nt++) {
        const int col = nt * 16 + l16;
        const bool ok = col < 40;
        const float as_c = ok ? as2[col] : 0.f;
        const float ad_c = ok ? ad2[col] : 0.f;
#pragma unroll
        for (int r = 0; r < 4; r++) {
            float v = acc[nt][r];
            if (ok) h2b[(size_t)(n0 + w * 16 + g * 4 + r) * 40 + col] = f2bf(v);
            ps[r] += v * as_c;
            pd[r] += v * ad_c;
        }
    }
#pragma unroll
    for (int r = 0; r < 4; r++)
#pragma unroll
        for (int off = 8; off > 0; off >>= 1) {
            ps[r] += __shfl_xor(ps[r], off, 64);
            pd[r] += __shfl_xor(pd[r], off, 64);
        }
    if (l16 == 0) {
#pragma unroll
        for (int r = 0; r < 4; r++) asrc[n0 + w * 16 + g * 4 + r] = ps[r];
    } else if (l16 == 1) {
#pragma unroll
        for (int r = 0; r < 4; r++) adst[n0 + w * 16 + g * 4 + r] = pd[r];
    }
}

// ====== layer 2 aggregation: 2 edges/half-wave, 8 edges/iter ======
__global__ __launch_bounds__(256) void node_agg2(
    const int* __restrict__ rowptr, const int* __restrict__ colsrc,
    const float* __restrict__ asrc, const float* __restrict__ adst,
    const ushort_t* __restrict__ h2b, const float* __restrict__ b2,
    float* __restrict__ out, int N)
{
    int n = (blockIdx.x * 256 + threadIdx.x) >> 6;
    int lane = threadIdx.x & 63;
    if (n >= N) return;
    const int r0 = rowptr[n], r1 = rowptr[n + 1];
    const int half = lane >> 5;
    const int l5 = lane & 31;
    const bool act = l5 < 20;
    const int cc = act ? 2 * l5 : 0;
    const float ad = adst[n];

    float acc0 = 0.f, acc1 = 0.f, ssum = 0.f;
    int j = r0;
    for (; j + 8 <= r1; j += 8) {
        int jA = j + half, jB = j + 2 + half, jC = j + 4 + half, jD = j + 6 + half;
        int sA = colsrc[jA], sB = colsrc[jB], sC = colsrc[jC], sD = colsrc[jD];
        float eA = asrc[sA] + ad, eB = asrc[sB] + ad, eC = asrc[sC] + ad, eD = asrc[sD] + ad;
        unsigned qA = *(const unsigned*)&h2b[(size_t)sA * 40 + cc];
        unsigned qB = *(const unsigned*)&h2b[(size_t)sB * 40 + cc];
        unsigned qC = *(const unsigned*)&h2b[(size_t)sC * 40 + cc];
        unsigned qD = *(const unsigned*)&h2b[(size_t)sD * 40 + cc];
        eA = eA > 0.f ? eA : NEG_SLOPE * eA;
        eB = eB > 0.f ? eB : NEG_SLOPE * eB;
        eC = eC > 0.f ? eC : NEG_SLOPE * eC;
        eD = eD > 0.f ? eD : NEG_SLOPE * eD;
        float pA = __expf(eA), pB = __expf(eB), pC = __expf(eC), pD = __expf(eD);
        ssum += (pA + pB) + (pC + pD);
        acc0 += pA * bflo(qA) + pB * bflo(qB) + pC * bflo(qC) + pD * bflo(qD);
        acc1 += pA * bfhi(qA) + pB * bfhi(qB) + pC * bfhi(qC) + pD * bfhi(qD);
    }
    for (; j < r1; j += 2) {
        int jj = j + half;
        bool valid = jj < r1;
        int s = colsrc[valid ? jj : r0];
        float e = asrc[s] + ad;
        unsigned q = *(const unsigned*)&h2b[(size_t)s * 40 + cc];
        e = e > 0.f ? e : NEG_SLOPE * e;
        float p = valid ? __expf(e) : 0.f;
        ssum += p;
        acc0 += p * bflo(q);
        acc1 += p * bfhi(q);
    }

    acc0 += __shfl_xor(acc0, 32, 64);
    acc1 += __shfl_xor(acc1, 32, 64);
    ssum += __shfl_xor(ssum, 32, 64);
    const float rz = 1.f / ssum;

    float v0 = act ? acc0 * rz + b2[cc]     : -1.0e30f;
    float v1 = act ? acc1 * rz + b2[cc + 1] : -1.0e30f;
    float mx = fmaxf(v0, v1);
#pragma unroll
    for (int off = 16; off > 0; off >>= 1) mx = fmaxf(mx, __shfl_xor(mx, off, 64));
    float pe = act ? __expf(v0 - mx) + __expf(v1 - mx) : 0.f;
#pragma unroll
    for (int off = 16; off > 0; off >>= 1) pe += __shfl_xor(pe, off, 64);
    float lse = mx + logf(pe);
    if (act && half == 0) {
        float2 o = make_float2(v0 - lse, v1 - lse);
        *(float2*)&out[(size_t)n * 40 + cc] = o;
    }
}

extern "C" void kernel_launch(void* const* d_in, const int* in_sizes, int n_in,
                              void* d_out, int out_size, void* d_ws, size_t ws_size,
                              hipStream_t stream)
{
    const float* x   = (const float*)d_in[0];
    const int*   ei  = (const int*)d_in[1];
    const float* W1  = (const float*)d_in[2];
    const float* as1 = (const float*)d_in[3];
    const float* ad1 = (const float*)d_in[4];
    const float* b1  = (const float*)d_in[5];
    const float* W2  = (const float*)d_in[6];
    const float* as2 = (const float*)d_in[7];
    const float* ad2 = (const float*)d_in[8];
    const float* b2  = (const float*)d_in[9];
    float* out = (float*)d_out;

    const int N  = in_sizes[0] / 128;
    const int E  = in_sizes[1] / 2;
    const int EP = E + N;
    const int NB = (N + 255) / 256;

    // workspace layout
    char* ws = (char*)d_ws;
    ushort_t* h1b  = (ushort_t*)ws;                        // N*256 bf16
    ushort_t* a1b  = h1b + (size_t)N * 256;                // N*256 bf16
    float* asrc    = (float*)(a1b + (size_t)N * 256);      // N*4
    float* adst    = asrc + (size_t)N * 4;                 // N*4
    int*   rowptr  = (int*)(adst + (size_t)N * 4);         // N+1
    int*   colsrc  = rowptr + (N + 1);                     // EP
    int*   deg     = colsrc + EP;                          // N
    ushort_t* h2b  = (ushort_t*)(deg + N);                 // N*40 bf16
    int*   bsum    = (int*)(h2b + (size_t)N * 40 + 16);    // NB (+pad for OOB-safe uint reads)
    ushort_t* w1p  = (ushort_t*)(bsum + NB);               // 32768 bf16
    ushort_t* w2p  = w1p + 32768;                          // 12288 bf16

    // ---- CSR build + weight prepack (fused) ----
    hipMemsetAsync(deg, 0, (size_t)N * sizeof(int), stream);
    int egrid = (EP + 255) / 256;
    hist_prepack_kernel<<<egrid, 256, 0, stream>>>(ei, E, EP, deg, W1, W2, w1p, w2p);
    block_sum_kernel<<<NB, 256, 0, stream>>>(deg, bsum, N);
    block_scan_kernel<<<NB, 256, 0, stream>>>(deg, bsum, rowptr, N, NB);
    scatter_kernel<<<egrid, 256, 0, stream>>>(ei, E, EP, rowptr, deg, colsrc);

    // ---- layer 1 ----
    gemm1_mfma<<<N / 64, 256, 0, stream>>>(x, w1p, as1, ad1, h1b, asrc, adst, N);
    node_agg1<<<(N * 64 + 255) / 256, 256, 0, stream>>>(rowptr, colsrc, asrc, adst, h1b, b1, a1b, N);

    // ---- layer 2 ----
    gemm2_mfma<<<N / 64, 256, 0, stream>>>(a1b, w2p, as2, ad2, h2b, asrc, adst, N);
    node_agg2<<<(N * 64 + 255) / 256, 256, 0, stream>>>(rowptr, colsrc, asrc, adst, h2b, b2, out, N);
}